// Round 1
// baseline (198.956 us; speedup 1.0000x reference)
//
#include <hip/hip_runtime.h>

#define S_DIM 4096
#define H_DIM 16
#define D_DIM 64
#define N_BLK 64          // S / 64 query blocks
#define NEG_INF_F (-1e30f)
#define QSCALE 0.125f     // 1/sqrt(64), exact

typedef __attribute__((ext_vector_type(4))) float f32x4;
typedef __attribute__((ext_vector_type(8))) short s16x8;
typedef __attribute__((ext_vector_type(4))) unsigned int u32x4;
typedef __attribute__((ext_vector_type(2))) unsigned int u32x2;

__device__ __forceinline__ unsigned int fbits(float f) {
    return __builtin_bit_cast(unsigned int, f);
}
// pack two floats -> two bf16 (round-half-up; inputs never NaN here). lo=a, hi=b
__device__ __forceinline__ unsigned int pkbf(float a, float b) {
    return __builtin_amdgcn_perm(fbits(b) + 0x8000u, fbits(a) + 0x8000u, 0x07060302u);
}

// Block = 8 waves (512 thr), 4 query blocks n0..n0+3. Wave w owns HALF of query
// block n = n0 + (w>>1): qt tiles {qt0, qt0+1}, qt0 = (w&1)*2.
// Rationale vs 4-wave version: LDS (64 KB) caps us at 2 blocks/CU; with 4 waves
// that was 8 waves/CU (2/SIMD) -> latency-bound (all pipes <27%). 8 waves/block
// doubles residency to 16 waves/CU (4/SIMD). K load+convert is duplicated
// between sibling waves (L2-served; VALU had headroom at 22%).
// Prologue: all 8 V^T tiles (j = n0-2 .. n0+5) staged to LDS as bf16 pairs, ONE
// barrier. Main loop (5 active stages per wave, NO barriers):
//   K A-fragments loaded directly global->VGPR (coalesced; L2/L3 absorbs
//   re-reads), S^T = K x Q^T -> lane holds S[query=l16][key=kt*16+4*quad+r];
//   online softmax; lane's exp'ed values form the PV A-fragment directly
//   (k-index permuted, V B-frags read from LDS with matching permutation).
// V^T LDS layout: row d (0..63), 512 keys as 256 u32 bf16-pairs, column ROTATED
// by 8*d shorts (mod 512) so reads/writes spread across banks.
__global__ __launch_bounds__(512, 4) void bsattn_kernel(
    const float* __restrict__ qg, const float* __restrict__ kg,
    const float* __restrict__ vg, float* __restrict__ outg)
{
    __shared__ unsigned int lds_vt[D_DIM * 256];   // 64 KB: V^T bf16 pairs, rotated

    const int tid  = threadIdx.x;
    const int w    = tid >> 6;                   // 0..7
    const int lane = tid & 63;
    const int quad = lane >> 4;
    const int l16  = lane & 15;

    const int b   = blockIdx.z;
    const int h   = blockIdx.y;
    const int n0  = blockIdx.x << 2;
    const int n   = n0 + (w >> 1);               // this wave's query block
    const int qt0 = (w & 1) << 1;                // first qt tile owned by this wave

    // ---- Q fragments (B-operand): bq[qq][hh], pre-scaled, bf16 ----
    s16x8 bq[2][2];
#pragma unroll
    for (int qq = 0; qq < 2; ++qq) {
        const int qt = qt0 + qq;
        const size_t qrow = ((size_t)(b * S_DIM + n * 64 + qt * 16 + l16) * H_DIM + h) * D_DIM;
#pragma unroll
        for (int hh = 0; hh < 2; ++hh) {
            const float4* qp = reinterpret_cast<const float4*>(qg + qrow + hh * 32 + quad * 8);
            float4 f0 = qp[0];
            float4 f1 = qp[1];
            u32x4 u;
            u.x = pkbf(f0.x * QSCALE, f0.y * QSCALE);
            u.y = pkbf(f0.z * QSCALE, f0.w * QSCALE);
            u.z = pkbf(f1.x * QSCALE, f1.y * QSCALE);
            u.w = pkbf(f1.z * QSCALE, f1.w * QSCALE);
            bq[qq][hh] = __builtin_bit_cast(s16x8, u);
        }
    }

    // ---- V^T staging: 8 tiles x 32 row-pairs x 2 d-halves = 512 slots ----
    {
        const int jt = tid >> 6;                 // 0..7 tile (wave-uniform)
        const int sp = (tid >> 1) & 31;          // row-pair index
        const int dh = tid & 1;                  // d-half (0: d<32, 1: d>=32)
        const int jv = n0 - 2 + jt;
        if (jv >= 0 && jv < N_BLK) {
            const float* v0p = vg + ((size_t)(b * S_DIM + jv * 64 + 2 * sp) * H_DIM + h) * D_DIM;
            const float* v1p = v0p + H_DIM * D_DIM;
            const int craw = jt * 64 + 2 * sp;   // raw column (key index) of this pair
#pragma unroll
            for (int ch = 0; ch < 2; ++ch) {     // 16 d-values per chunk
                const int d0 = dh * 32 + ch * 16;
                const float4* ap = reinterpret_cast<const float4*>(v0p + d0);
                const float4* bp = reinterpret_cast<const float4*>(v1p + d0);
                float4 a0 = ap[0], a1 = ap[1], a2 = ap[2], a3 = ap[3];
                float4 b0 = bp[0], b1 = bp[1], b2 = bp[2], b3 = bp[3];
                float av[16] = {a0.x,a0.y,a0.z,a0.w, a1.x,a1.y,a1.z,a1.w,
                                a2.x,a2.y,a2.z,a2.w, a3.x,a3.y,a3.z,a3.w};
                float bv[16] = {b0.x,b0.y,b0.z,b0.w, b1.x,b1.y,b1.z,b1.w,
                                b2.x,b2.y,b2.z,b2.w, b3.x,b3.y,b3.z,b3.w};
#pragma unroll
                for (int i = 0; i < 16; ++i) {
                    const int d = d0 + i;
                    lds_vt[d * 256 + (((craw + 8 * d) & 511) >> 1)] = pkbf(av[i], bv[i]);
                }
            }
        }
    }

    f32x4 o[2][4];                   // O accum [qq][dt], C layout (row=query, col=d)
    float m_run[2], l_run[2];
#pragma unroll
    for (int qq = 0; qq < 2; ++qq) {
        m_run[qq] = NEG_INF_F; l_run[qq] = 0.f;
#pragma unroll
        for (int dt = 0; dt < 4; ++dt) o[qq][dt] = (f32x4){0.f, 0.f, 0.f, 0.f};
    }

    __syncthreads();                 // V^T visible; no further barriers

    const int colb = quad * 4 + 8 * l16;     // read-column base (rotation part w/o tile/dt)

    for (int t = 0; t < 5; ++t) {
        const int j = n - 2 + t;             // key block (wave-uniform)
        if (j < 0 || j >= N_BLK) continue;
        const int ji = (w >> 1) + t;         // staged tile index = j - n0 + 2

        // ---- K A-fragments direct from global (coalesced 16-row x 128B chunks) ----
        float4 kf[4][2][2];
#pragma unroll
        for (int kt = 0; kt < 4; ++kt) {
            const size_t krow = ((size_t)(b * S_DIM + j * 64 + kt * 16 + l16) * H_DIM + h) * D_DIM + quad * 8;
#pragma unroll
            for (int hh = 0; hh < 2; ++hh) {
                const float4* kp = reinterpret_cast<const float4*>(kg + krow + hh * 32);
                kf[kt][hh][0] = kp[0];
                kf[kt][hh][1] = kp[1];
            }
        }
        s16x8 kbf[4][2];
#pragma unroll
        for (int kt = 0; kt < 4; ++kt)
#pragma unroll
            for (int hh = 0; hh < 2; ++hh) {
                u32x4 u;
                u.x = pkbf(kf[kt][hh][0].x, kf[kt][hh][0].y);
                u.y = pkbf(kf[kt][hh][0].z, kf[kt][hh][0].w);
                u.z = pkbf(kf[kt][hh][1].x, kf[kt][hh][1].y);
                u.w = pkbf(kf[kt][hh][1].z, kf[kt][hh][1].w);
                kbf[kt][hh] = __builtin_bit_cast(s16x8, u);
            }

        // ---- per qq: S^T = K x Q^T, online softmax; P stays in registers ----
        s16x8 pa[2][2];
#pragma unroll
        for (int qq = 0; qq < 2; ++qq) {
            f32x4 sa[4];
#pragma unroll
            for (int kt = 0; kt < 4; ++kt) {
                f32x4 z = {0.f, 0.f, 0.f, 0.f};
                f32x4 a0 = __builtin_amdgcn_mfma_f32_16x16x32_bf16(kbf[kt][0], bq[qq][0], z, 0, 0, 0);
                sa[kt]   = __builtin_amdgcn_mfma_f32_16x16x32_bf16(kbf[kt][1], bq[qq][1], a0, 0, 0, 0);
            }
            float mx = NEG_INF_F;
#pragma unroll
            for (int kt = 0; kt < 4; ++kt)
#pragma unroll
                for (int r = 0; r < 4; ++r) mx = fmaxf(mx, sa[kt][r]);
            mx = fmaxf(mx, __shfl_xor(mx, 16));
            mx = fmaxf(mx, __shfl_xor(mx, 32));
            const float mn = fmaxf(m_run[qq], mx);
            const float alpha = __expf(m_run[qq] - mn);
            m_run[qq] = mn;

            float rs = 0.f;
            unsigned int pk[4][2];
#pragma unroll
            for (int kt = 0; kt < 4; ++kt) {
                float e0 = __expf(sa[kt][0] - mn);
                float e1 = __expf(sa[kt][1] - mn);
                float e2 = __expf(sa[kt][2] - mn);
                float e3 = __expf(sa[kt][3] - mn);
                rs += (e0 + e1) + (e2 + e3);
                pk[kt][0] = pkbf(e0, e1);
                pk[kt][1] = pkbf(e2, e3);
            }
            rs += __shfl_xor(rs, 16);
            rs += __shfl_xor(rs, 32);
            l_run[qq] = l_run[qq] * alpha + rs;

            float ab[4];
#pragma unroll
            for (int r = 0; r < 4; ++r)
                ab[r] = __shfl(alpha, (lane & 48) + quad * 4 + r);
#pragma unroll
            for (int dt = 0; dt < 4; ++dt)
#pragma unroll
                for (int r = 0; r < 4; ++r) o[qq][dt][r] *= ab[r];

            pa[qq][0] = __builtin_bit_cast(s16x8, (u32x4){pk[0][0], pk[0][1], pk[1][0], pk[1][1]});
            pa[qq][1] = __builtin_bit_cast(s16x8, (u32x4){pk[2][0], pk[2][1], pk[3][0], pk[3][1]});
        }

        // ---- PV: O += P x V (B-frags from rotated V^T LDS, permuted key order) ----
        const int cb0 = ji * 64 + colb;
#pragma unroll
        for (int dt = 0; dt < 4; ++dt) {
            const int d = dt * 16 + l16;
            const unsigned int* vrow = lds_vt + d * 256;
            const int cb = cb0 + 128 * dt;
            u32x2 v00 = *reinterpret_cast<const u32x2*>(vrow + (((cb     ) & 511) >> 1));
            u32x2 v01 = *reinterpret_cast<const u32x2*>(vrow + (((cb + 16) & 511) >> 1));
            u32x2 v10 = *reinterpret_cast<const u32x2*>(vrow + (((cb + 32) & 511) >> 1));
            u32x2 v11 = *reinterpret_cast<const u32x2*>(vrow + (((cb + 48) & 511) >> 1));
            s16x8 vf0 = __builtin_bit_cast(s16x8, (u32x4){v00.x, v00.y, v01.x, v01.y});
            s16x8 vf1 = __builtin_bit_cast(s16x8, (u32x4){v10.x, v10.y, v11.x, v11.y});
#pragma unroll
            for (int qq = 0; qq < 2; ++qq) {
                o[qq][dt] = __builtin_amdgcn_mfma_f32_16x16x32_bf16(pa[qq][0], vf0, o[qq][dt], 0, 0, 0);
                o[qq][dt] = __builtin_amdgcn_mfma_f32_16x16x32_bf16(pa[qq][1], vf1, o[qq][dt], 0, 0, 0);
            }
        }
    }

    // ---- epilogue: broadcast l to row layout, normalize, store ----
#pragma unroll
    for (int qq = 0; qq < 2; ++qq) {
        const int qt = qt0 + qq;
#pragma unroll
        for (int r = 0; r < 4; ++r) {
            const float lb = __shfl(l_run[qq], (lane & 48) + quad * 4 + r);
            const float inv = 1.0f / lb;
            const int row = n * 64 + qt * 16 + quad * 4 + r;
            float* op = outg + ((size_t)(b * S_DIM + row) * H_DIM + h) * D_DIM + l16;
#pragma unroll
            for (int dt = 0; dt < 4; ++dt)
                op[dt * 16] = o[qq][dt][r] * inv;
        }
    }
}

extern "C" void kernel_launch(void* const* d_in, const int* in_sizes, int n_in,
                              void* d_out, int out_size, void* d_ws, size_t ws_size,
                              hipStream_t stream) {
    const float* q = (const float*)d_in[0];
    const float* k = (const float*)d_in[1];
    const float* v = (const float*)d_in[2];
    float* out = (float*)d_out;
    const int B = in_sizes[0] / (S_DIM * H_DIM * D_DIM);   // = 2
    dim3 grid(N_BLK / 4, H_DIM, B);
    dim3 block(512);
    hipLaunchKernelGGL(bsattn_kernel, grid, block, 0, stream, q, k, v, out);
}

// Round 2
// 170.479 us; speedup vs baseline: 1.1670x; 1.1670x over previous
//
#include <hip/hip_runtime.h>

#define S_DIM 4096
#define H_DIM 16
#define D_DIM 64
#define N_BLK 64          // S / 64 query blocks
#define NEG_INF_F (-1e30f)
#define QSCALE 0.125f     // 1/sqrt(64), exact

typedef __attribute__((ext_vector_type(4))) float f32x4;
typedef __attribute__((ext_vector_type(8))) short s16x8;
typedef __attribute__((ext_vector_type(4))) unsigned int u32x4;
typedef __attribute__((ext_vector_type(2))) unsigned int u32x2;

__device__ __forceinline__ unsigned int fbits(float f) {
    return __builtin_bit_cast(unsigned int, f);
}
// pack two floats -> two bf16 (round-half-up; inputs never NaN here). lo=a, hi=b
__device__ __forceinline__ unsigned int pkbf(float a, float b) {
    return __builtin_amdgcn_perm(fbits(b) + 0x8000u, fbits(a) + 0x8000u, 0x07060302u);
}

// Block = 8 waves (512 thr), 4 query blocks n0..n0+3. Wave w owns HALF of query
// block n = n0 + (w>>1): qt tiles {qt0, qt0+1}, qt0 = (w&1)*2.
// LDS (64 KB) caps residency at 2 blocks/CU; 8 waves/block -> 16 waves/CU
// (4/SIMD), double the 4-wave version. K load+convert duplicated between
// sibling waves (L2-served; VALU has headroom).
// __launch_bounds__(512, 2): hipcc caps VGPR at 256/min_waves. (512,4) capped
// at 64 VGPR -> massive scratch spill (FETCH +98MB, WRITE +42MB, 105us).
// (512,2) -> cap 128; kernel needs ~120 -> no spill, and <=128 still allows
// the LDS-limited 16 waves/CU.
// Prologue: all 8 V^T tiles (j = n0-2 .. n0+5) staged to LDS as bf16 pairs,
// ONE barrier. Wave w stages tile w; lane -> (sp = lane&31 row-pair,
// dh = lane>>5 d-half) so each 32-lane LDS phase has uniform d and 32 distinct
// banks (dh=tid&1 variant put d/d+32 pairs in one phase -> same bank -> 254K
// conflicts).
// Main loop (5 active stages per wave, NO barriers):
//   K A-fragments loaded directly global->VGPR (coalesced; L2/L3 absorbs
//   re-reads), S^T = K x Q^T -> lane holds S[query=l16][key=kt*16+4*quad+r];
//   online softmax; lane's exp'ed values form the PV A-fragment directly
//   (k-index permuted, V B-frags read from LDS with matching permutation).
// V^T LDS layout: row d (0..63), 512 keys as 256 u32 bf16-pairs, column ROTATED
// by 8*d shorts (mod 512) so reads/writes spread across banks.
__global__ __launch_bounds__(512, 2) void bsattn_kernel(
    const float* __restrict__ qg, const float* __restrict__ kg,
    const float* __restrict__ vg, float* __restrict__ outg)
{
    __shared__ unsigned int lds_vt[D_DIM * 256];   // 64 KB: V^T bf16 pairs, rotated

    const int tid  = threadIdx.x;
    const int w    = tid >> 6;                   // 0..7
    const int lane = tid & 63;
    const int quad = lane >> 4;
    const int l16  = lane & 15;

    const int b   = blockIdx.z;
    const int h   = blockIdx.y;
    const int n0  = blockIdx.x << 2;
    const int n   = n0 + (w >> 1);               // this wave's query block
    const int qt0 = (w & 1) << 1;                // first qt tile owned by this wave

    // ---- Q fragments (B-operand): bq[qq][hh], pre-scaled, bf16 ----
    s16x8 bq[2][2];
#pragma unroll
    for (int qq = 0; qq < 2; ++qq) {
        const int qt = qt0 + qq;
        const size_t qrow = ((size_t)(b * S_DIM + n * 64 + qt * 16 + l16) * H_DIM + h) * D_DIM;
#pragma unroll
        for (int hh = 0; hh < 2; ++hh) {
            const float4* qp = reinterpret_cast<const float4*>(qg + qrow + hh * 32 + quad * 8);
            float4 f0 = qp[0];
            float4 f1 = qp[1];
            u32x4 u;
            u.x = pkbf(f0.x * QSCALE, f0.y * QSCALE);
            u.y = pkbf(f0.z * QSCALE, f0.w * QSCALE);
            u.z = pkbf(f1.x * QSCALE, f1.y * QSCALE);
            u.w = pkbf(f1.z * QSCALE, f1.w * QSCALE);
            bq[qq][hh] = __builtin_bit_cast(s16x8, u);
        }
    }

    // ---- V^T staging: wave w stages tile w; lane -> (row-pair sp, d-half dh) ----
    {
        const int jt = w;                        // 0..7 tile (wave-uniform)
        const int sp = lane & 31;                // row-pair index
        const int dh = lane >> 5;                // d-half (0: d<32, 1: d>=32)
        const int jv = n0 - 2 + jt;
        if (jv >= 0 && jv < N_BLK) {
            const float* v0p = vg + ((size_t)(b * S_DIM + jv * 64 + 2 * sp) * H_DIM + h) * D_DIM;
            const float* v1p = v0p + H_DIM * D_DIM;
            const int craw = jt * 64 + 2 * sp;   // raw column (key index) of this pair
#pragma unroll
            for (int ch = 0; ch < 2; ++ch) {     // 16 d-values per chunk
                const int d0 = dh * 32 + ch * 16;
                const float4* ap = reinterpret_cast<const float4*>(v0p + d0);
                const float4* bp = reinterpret_cast<const float4*>(v1p + d0);
                float4 a0 = ap[0], a1 = ap[1], a2 = ap[2], a3 = ap[3];
                float4 b0 = bp[0], b1 = bp[1], b2 = bp[2], b3 = bp[3];
                float av[16] = {a0.x,a0.y,a0.z,a0.w, a1.x,a1.y,a1.z,a1.w,
                                a2.x,a2.y,a2.z,a2.w, a3.x,a3.y,a3.z,a3.w};
                float bv[16] = {b0.x,b0.y,b0.z,b0.w, b1.x,b1.y,b1.z,b1.w,
                                b2.x,b2.y,b2.z,b2.w, b3.x,b3.y,b3.z,b3.w};
#pragma unroll
                for (int i = 0; i < 16; ++i) {
                    const int d = d0 + i;
                    lds_vt[d * 256 + (((craw + 8 * d) & 511) >> 1)] = pkbf(av[i], bv[i]);
                }
            }
        }
    }

    f32x4 o[2][4];                   // O accum [qq][dt], C layout (row=query, col=d)
    float m_run[2], l_run[2];
#pragma unroll
    for (int qq = 0; qq < 2; ++qq) {
        m_run[qq] = NEG_INF_F; l_run[qq] = 0.f;
#pragma unroll
        for (int dt = 0; dt < 4; ++dt) o[qq][dt] = (f32x4){0.f, 0.f, 0.f, 0.f};
    }

    __syncthreads();                 // V^T visible; no further barriers

    const int colb = quad * 4 + 8 * l16;     // read-column base (rotation part w/o tile/dt)

    for (int t = 0; t < 5; ++t) {
        const int j = n - 2 + t;             // key block (wave-uniform)
        if (j < 0 || j >= N_BLK) continue;
        const int ji = (w >> 1) + t;         // staged tile index = j - n0 + 2

        // ---- K A-fragments direct from global (coalesced 16-row x 128B chunks) ----
        float4 kf[4][2][2];
#pragma unroll
        for (int kt = 0; kt < 4; ++kt) {
            const size_t krow = ((size_t)(b * S_DIM + j * 64 + kt * 16 + l16) * H_DIM + h) * D_DIM + quad * 8;
#pragma unroll
            for (int hh = 0; hh < 2; ++hh) {
                const float4* kp = reinterpret_cast<const float4*>(kg + krow + hh * 32);
                kf[kt][hh][0] = kp[0];
                kf[kt][hh][1] = kp[1];
            }
        }
        s16x8 kbf[4][2];
#pragma unroll
        for (int kt = 0; kt < 4; ++kt)
#pragma unroll
            for (int hh = 0; hh < 2; ++hh) {
                u32x4 u;
                u.x = pkbf(kf[kt][hh][0].x, kf[kt][hh][0].y);
                u.y = pkbf(kf[kt][hh][0].z, kf[kt][hh][0].w);
                u.z = pkbf(kf[kt][hh][1].x, kf[kt][hh][1].y);
                u.w = pkbf(kf[kt][hh][1].z, kf[kt][hh][1].w);
                kbf[kt][hh] = __builtin_bit_cast(s16x8, u);
            }

        // ---- per qq: S^T = K x Q^T, online softmax; P stays in registers ----
        s16x8 pa[2][2];
#pragma unroll
        for (int qq = 0; qq < 2; ++qq) {
            f32x4 sa[4];
#pragma unroll
            for (int kt = 0; kt < 4; ++kt) {
                f32x4 z = {0.f, 0.f, 0.f, 0.f};
                f32x4 a0 = __builtin_amdgcn_mfma_f32_16x16x32_bf16(kbf[kt][0], bq[qq][0], z, 0, 0, 0);
                sa[kt]   = __builtin_amdgcn_mfma_f32_16x16x32_bf16(kbf[kt][1], bq[qq][1], a0, 0, 0, 0);
            }
            float mx = NEG_INF_F;
#pragma unroll
            for (int kt = 0; kt < 4; ++kt)
#pragma unroll
                for (int r = 0; r < 4; ++r) mx = fmaxf(mx, sa[kt][r]);
            mx = fmaxf(mx, __shfl_xor(mx, 16));
            mx = fmaxf(mx, __shfl_xor(mx, 32));
            const float mn = fmaxf(m_run[qq], mx);
            const float alpha = __expf(m_run[qq] - mn);
            m_run[qq] = mn;

            float rs = 0.f;
            unsigned int pk[4][2];
#pragma unroll
            for (int kt = 0; kt < 4; ++kt) {
                float e0 = __expf(sa[kt][0] - mn);
                float e1 = __expf(sa[kt][1] - mn);
                float e2 = __expf(sa[kt][2] - mn);
                float e3 = __expf(sa[kt][3] - mn);
                rs += (e0 + e1) + (e2 + e3);
                pk[kt][0] = pkbf(e0, e1);
                pk[kt][1] = pkbf(e2, e3);
            }
            rs += __shfl_xor(rs, 16);
            rs += __shfl_xor(rs, 32);
            l_run[qq] = l_run[qq] * alpha + rs;

            float ab[4];
#pragma unroll
            for (int r = 0; r < 4; ++r)
                ab[r] = __shfl(alpha, (lane & 48) + quad * 4 + r);
#pragma unroll
            for (int dt = 0; dt < 4; ++dt)
#pragma unroll
                for (int r = 0; r < 4; ++r) o[qq][dt][r] *= ab[r];

            pa[qq][0] = __builtin_bit_cast(s16x8, (u32x4){pk[0][0], pk[0][1], pk[1][0], pk[1][1]});
            pa[qq][1] = __builtin_bit_cast(s16x8, (u32x4){pk[2][0], pk[2][1], pk[3][0], pk[3][1]});
        }

        // ---- PV: O += P x V (B-frags from rotated V^T LDS, permuted key order) ----
        const int cb0 = ji * 64 + colb;
#pragma unroll
        for (int dt = 0; dt < 4; ++dt) {
            const int d = dt * 16 + l16;
            const unsigned int* vrow = lds_vt + d * 256;
            const int cb = cb0 + 128 * dt;
            u32x2 v00 = *reinterpret_cast<const u32x2*>(vrow + (((cb     ) & 511) >> 1));
            u32x2 v01 = *reinterpret_cast<const u32x2*>(vrow + (((cb + 16) & 511) >> 1));
            u32x2 v10 = *reinterpret_cast<const u32x2*>(vrow + (((cb + 32) & 511) >> 1));
            u32x2 v11 = *reinterpret_cast<const u32x2*>(vrow + (((cb + 48) & 511) >> 1));
            s16x8 vf0 = __builtin_bit_cast(s16x8, (u32x4){v00.x, v00.y, v01.x, v01.y});
            s16x8 vf1 = __builtin_bit_cast(s16x8, (u32x4){v10.x, v10.y, v11.x, v11.y});
#pragma unroll
            for (int qq = 0; qq < 2; ++qq) {
                o[qq][dt] = __builtin_amdgcn_mfma_f32_16x16x32_bf16(pa[qq][0], vf0, o[qq][dt], 0, 0, 0);
                o[qq][dt] = __builtin_amdgcn_mfma_f32_16x16x32_bf16(pa[qq][1], vf1, o[qq][dt], 0, 0, 0);
            }
        }
    }

    // ---- epilogue: broadcast l to row layout, normalize, store ----
#pragma unroll
    for (int qq = 0; qq < 2; ++qq) {
        const int qt = qt0 + qq;
#pragma unroll
        for (int r = 0; r < 4; ++r) {
            const float lb = __shfl(l_run[qq], (lane & 48) + quad * 4 + r);
            const float inv = 1.0f / lb;
            const int row = n * 64 + qt * 16 + quad * 4 + r;
            float* op = outg + ((size_t)(b * S_DIM + row) * H_DIM + h) * D_DIM + l16;
#pragma unroll
            for (int dt = 0; dt < 4; ++dt)
                op[dt * 16] = o[qq][dt][r] * inv;
        }
    }
}

extern "C" void kernel_launch(void* const* d_in, const int* in_sizes, int n_in,
                              void* d_out, int out_size, void* d_ws, size_t ws_size,
                              hipStream_t stream) {
    const float* q = (const float*)d_in[0];
    const float* k = (const float*)d_in[1];
    const float* v = (const float*)d_in[2];
    float* out = (float*)d_out;
    const int B = in_sizes[0] / (S_DIM * H_DIM * D_DIM);   // = 2
    dim3 grid(N_BLK / 4, H_DIM, B);
    dim3 block(512);
    hipLaunchKernelGGL(bsattn_kernel, grid, block, 0, stream, q, k, v, out);
}